// Round 6
// baseline (1954.224 us; speedup 1.0000x reference)
//
#include <hip/hip_runtime.h>
#include <hip/hip_bf16.h>
#include <math.h>

#define Bq 16
#define Tq 256
#define Hq 512
#define Vq 32000
#define Gq 1536
#define NWG 16
#define LBLK 384           // persistent logits blocks
#define NBI 167            // ceil(32000/192) N-tiles (166 full + tail 128)
#define NTILES (32 * NBI)  // 32 m-tiles (8 timesteps each) x 167

typedef __attribute__((ext_vector_type(8))) short short8;
typedef __attribute__((ext_vector_type(4))) float f32x4;
typedef unsigned long long u64;

typedef const __attribute__((address_space(1))) void g_void;
typedef __attribute__((address_space(3))) void l_void;

__device__ __forceinline__ unsigned short f2bf(float f) {
    union { float f; unsigned int u; } v; v.f = f;
    unsigned int r = v.u + 0x7fffu + ((v.u >> 16) & 1u);
    return (unsigned short)(r >> 16);
}
__device__ __forceinline__ float bf2f(unsigned short h) {
    union { unsigned int u; float f; } v; v.u = ((unsigned int)h) << 16;
    return v.f;
}
__device__ __forceinline__ float sigm(float x) { return 1.0f / (1.0f + __expf(-x)); }
__device__ __forceinline__ float tanh_fast(float x) {
    float e = __expf(-2.0f * x);
    return (1.0f - e) / (1.0f + e);
}

// ---------------------------------------------------------------------------
// prep: cast E->bf16; split W_ih/W_hh; ZERO all Hpk stamps (gates this launch)
// ---------------------------------------------------------------------------
__global__ void prep_kernel(const float* __restrict__ E, const float* __restrict__ Wih,
                            const float* __restrict__ Whh,
                            unsigned short* __restrict__ Ebf,
                            unsigned short* __restrict__ WihHi, unsigned short* __restrict__ WihLo,
                            unsigned short* __restrict__ WhhHi, unsigned short* __restrict__ WhhLo,
                            u64* __restrict__ Hpk) {
    long tid = (long)blockIdx.x * blockDim.x + threadIdx.x;
    long stride = (long)gridDim.x * blockDim.x;
    for (long i = tid; i < (long)Vq * Hq; i += stride) Ebf[i] = f2bf(E[i]);
    for (long i = tid; i < (long)Gq * Hq; i += stride) {
        float w = Wih[i]; unsigned short hi = f2bf(w);
        WihHi[i] = hi; WihLo[i] = f2bf(w - bf2f(hi));
        w = Whh[i]; hi = f2bf(w);
        WhhHi[i] = hi; WhhLo[i] = f2bf(w - bf2f(hi));
    }
    for (long i = tid; i < (long)Tq * 8192; i += stride) Hpk[i] = 0ull;
}

// ---------------------------------------------------------------------------
// gi: gi_all[t,b,:] = E[tok(t,b)] @ W_ih^T + b_ih   (split-bf16)
// ---------------------------------------------------------------------------
__launch_bounds__(384)
__global__ void gi_kernel(const int* __restrict__ target, const float* __restrict__ E,
                          const unsigned short* __restrict__ WihHi,
                          const unsigned short* __restrict__ WihLo,
                          const float* __restrict__ b_ih, float* __restrict__ gi_all) {
    __shared__ __align__(16) unsigned short Ahi[16][520];
    __shared__ __align__(16) unsigned short Alo[16][520];
    __shared__ int toks[16];
    int t = blockIdx.x, gb = blockIdx.y;
    int tid = threadIdx.x;
    if (tid < 16) toks[tid] = (t == 0) ? 1 : target[tid * Tq + (t - 1)];  // START=1
    __syncthreads();
    for (int idx = tid; idx < 16 * Hq; idx += 384) {
        int r = idx >> 9, k = idx & 511;
        float v = E[(long)toks[r] * Hq + k];
        unsigned short hi = f2bf(v);
        Ahi[r][k] = hi; Alo[r][k] = f2bf(v - bf2f(hi));
    }
    __syncthreads();
    int wave = tid >> 6, lane = tid & 63;
    int gcb = gb * 96 + wave * 16;
    int row = lane & 15, kg = (lane >> 4) * 8;
    const unsigned short* bh = WihHi + (long)(gcb + row) * Hq;
    const unsigned short* bl = WihLo + (long)(gcb + row) * Hq;
    f32x4 aHH = {0,0,0,0}, aHL = {0,0,0,0}, aLH = {0,0,0,0};
#pragma unroll
    for (int ks = 0; ks < 16; ++ks) {
        int k0 = ks * 32 + kg;
        short8 ah = *(const short8*)&Ahi[row][k0];
        short8 al = *(const short8*)&Alo[row][k0];
        short8 wh = *(const short8*)&bh[k0];
        short8 wl = *(const short8*)&bl[k0];
        aHH = __builtin_amdgcn_mfma_f32_16x16x32_bf16(ah, wh, aHH, 0, 0, 0);
        aHL = __builtin_amdgcn_mfma_f32_16x16x32_bf16(ah, wl, aHL, 0, 0, 0);
        aLH = __builtin_amdgcn_mfma_f32_16x16x32_bf16(al, wh, aLH, 0, 0, 0);
    }
    int g = gcb + row;
    float bi = b_ih[g];
#pragma unroll
    for (int q = 0; q < 4; ++q) {
        int b = (lane >> 4) * 4 + q;
        gi_all[((long)(t * 16 + b)) * Gq + g] = aHH[q] + aHL[q] + aLH[q] + bi;
    }
}

// ---------------------------------------------------------------------------
// fused: blocks 0..15 = rnn (serial GRU, stamped coherent h exchange);
// blocks 16..399 = persistent logits consumers, gated by the SAME stamps.
// Capacity proof: 400 blocks x 42KB LDS/384thr -> >=3 blocks/CU resident
// regardless of dispatch order; all spins bounded.
// ---------------------------------------------------------------------------
__launch_bounds__(384, 1)
__global__ void fused_kernel(const float* __restrict__ h0,
                             const unsigned short* __restrict__ WhhHi,
                             const unsigned short* __restrict__ WhhLo,
                             const float* __restrict__ b_hh,
                             const float* __restrict__ gi_all,
                             u64* Hpk,
                             const unsigned short* __restrict__ Ebf,
                             const float* __restrict__ b_out,
                             float* __restrict__ out) {
    __shared__ __align__(16) char smem[41984];
    int tid = threadIdx.x;
    int lane = tid & 63;

    if (blockIdx.x < NWG) {
        // ================= RNN role (R5-validated, H_bf store removed) =====
        __builtin_amdgcn_s_setprio(1);   // serial critical path: win arbitration
        unsigned short (*Ahi)[520] = (unsigned short (*)[520])smem;
        unsigned short (*Alo)[520] = (unsigned short (*)[520])(smem + 16640);
        float (*gbuf)[16][33] = (float (*)[16][33])(smem + 33280);
        int w = blockIdx.x;
        int wave = tid >> 6;
        int gate = wave >> 1;
        int gcol = gate * 512 + w * 32 + (wave & 1) * 16;
        int row = lane & 15, kg = (lane >> 4) * 8;
        const unsigned short* bhp = WhhHi + (long)(gcol + row) * Hq;
        const unsigned short* blp = WhhLo + (long)(gcol + row) * Hq;
        short8 Bh[16], Bl[16];
#pragma unroll
        for (int ks = 0; ks < 16; ++ks) {
            Bh[ks] = *(const short8*)&bhp[ks * 32 + kg];
            Bl[ks] = *(const short8*)&blp[ks * 32 + kg];
        }
        float bhh = b_hh[gcol + row];
        float gin[4];
#pragma unroll
        for (int q = 0; q < 4; ++q) {
            int b = (lane >> 4) * 4 + q;
            gin[q] = gi_all[(long)b * Gq + (gcol + row)];
        }
        for (int t = 0; t < Tq; ++t) {
            if (t == 0) {
                for (int idx = tid; idx < Bq * Hq; idx += 384) {
                    float v = h0[idx];
                    unsigned short hi = f2bf(v);
                    Ahi[idx >> 9][idx & 511] = hi;
                    Alo[idx >> 9][idx & 511] = f2bf(v - bf2f(hi));
                }
            } else {
                const u64* src = Hpk + (long)(t - 1) * 8192;
                u64 vb[22];
                bool ok;
                int guard = 0;
                do {
                    ok = true;
#pragma unroll
                    for (int k = 0; k < 21; ++k)
                        vb[k] = __hip_atomic_load(&src[tid + k * 384], __ATOMIC_RELAXED,
                                                  __HIP_MEMORY_SCOPE_AGENT);
                    if (tid < 128)
                        vb[21] = __hip_atomic_load(&src[8064 + tid], __ATOMIC_RELAXED,
                                                   __HIP_MEMORY_SCOPE_AGENT);
                    else
                        vb[21] = (u64)(unsigned int)t << 32;
#pragma unroll
                    for (int k = 0; k < 22; ++k)
                        ok = ok && ((int)(vb[k] >> 32) == t);
                } while (!ok && ++guard < 8192);
#pragma unroll
                for (int k = 0; k < 21; ++k) {
                    int i = tid + k * 384;
                    unsigned int d = (unsigned int)vb[k];
                    Ahi[i >> 9][i & 511] = (unsigned short)(d >> 16);
                    Alo[i >> 9][i & 511] = (unsigned short)d;
                }
                if (tid < 128) {
                    int i = 8064 + tid;
                    unsigned int d = (unsigned int)vb[21];
                    Ahi[i >> 9][i & 511] = (unsigned short)(d >> 16);
                    Alo[i >> 9][i & 511] = (unsigned short)d;
                }
            }
            __syncthreads();
            f32x4 xHH = {0,0,0,0}, xHL = {0,0,0,0}, xLH = {0,0,0,0};
            f32x4 yHH = {0,0,0,0}, yHL = {0,0,0,0}, yLH = {0,0,0,0};
#pragma unroll
            for (int ks = 0; ks < 8; ++ks) {
                int k0 = ks * 32 + kg;
                short8 ah = *(const short8*)&Ahi[row][k0];
                short8 al = *(const short8*)&Alo[row][k0];
                xHH = __builtin_amdgcn_mfma_f32_16x16x32_bf16(ah, Bh[ks], xHH, 0, 0, 0);
                xHL = __builtin_amdgcn_mfma_f32_16x16x32_bf16(ah, Bl[ks], xHL, 0, 0, 0);
                xLH = __builtin_amdgcn_mfma_f32_16x16x32_bf16(al, Bh[ks], xLH, 0, 0, 0);
            }
#pragma unroll
            for (int ks = 8; ks < 16; ++ks) {
                int k0 = ks * 32 + kg;
                short8 ah = *(const short8*)&Ahi[row][k0];
                short8 al = *(const short8*)&Alo[row][k0];
                yHH = __builtin_amdgcn_mfma_f32_16x16x32_bf16(ah, Bh[ks], yHH, 0, 0, 0);
                yHL = __builtin_amdgcn_mfma_f32_16x16x32_bf16(ah, Bl[ks], yHL, 0, 0, 0);
                yLH = __builtin_amdgcn_mfma_f32_16x16x32_bf16(al, Bh[ks], yLH, 0, 0, 0);
            }
            int jj = (wave & 1) * 16 + row;
#pragma unroll
            for (int q = 0; q < 4; ++q) {
                int b = (lane >> 4) * 4 + q;
                float ghv = (xHH[q] + yHH[q]) + (xHL[q] + yHL[q]) + (xLH[q] + yLH[q]) + bhh;
                if (gate < 2) gbuf[gate][b][jj] = ghv + gin[q];
                else { gbuf[2][b][jj] = gin[q]; gbuf[3][b][jj] = ghv; }
            }
            __syncthreads();
            if (tid < 256) {
                int b = tid >> 4, jp = tid & 15;
                int j0 = jp * 2, j1 = j0 + 1;
                int jc0 = w * 32 + j0;
                float r0 = sigm(gbuf[0][b][j0]);
                float z0 = sigm(gbuf[1][b][j0]);
                float n0 = tanh_fast(gbuf[2][b][j0] + r0 * gbuf[3][b][j0]);
                float hp0 = bf2f(Ahi[b][jc0]) + bf2f(Alo[b][jc0]);
                float hn0 = (1.0f - z0) * n0 + z0 * hp0;
                float r1 = sigm(gbuf[0][b][j1]);
                float z1 = sigm(gbuf[1][b][j1]);
                float n1 = tanh_fast(gbuf[2][b][j1] + r1 * gbuf[3][b][j1]);
                float hp1 = bf2f(Ahi[b][jc0 + 1]) + bf2f(Alo[b][jc0 + 1]);
                float hn1 = (1.0f - z1) * n1 + z1 * hp1;
                unsigned short h0h = f2bf(hn0), h1h = f2bf(hn1);
                unsigned short h0l = f2bf(hn0 - bf2f(h0h)), h1l = f2bf(hn1 - bf2f(h1h));
                u64 stamp = (u64)(unsigned int)(t + 1) << 32;
                long i0 = (long)t * 8192 + b * 512 + jc0;
                __hip_atomic_store(&Hpk[i0], stamp | ((unsigned int)h0h << 16) | h0l,
                                   __ATOMIC_RELAXED, __HIP_MEMORY_SCOPE_AGENT);
                __hip_atomic_store(&Hpk[i0 + 1], stamp | ((unsigned int)h1h << 16) | h1l,
                                   __ATOMIC_RELAXED, __HIP_MEMORY_SCOPE_AGENT);
            }
            int tp = (t + 1 < Tq) ? (t + 1) : t;
#pragma unroll
            for (int q = 0; q < 4; ++q) {
                int b = (lane >> 4) * 4 + q;
                gin[q] = gi_all[((long)(tp * 16 + b)) * Gq + (gcol + row)];
            }
            __syncthreads();
        }
    } else {
        // ================= logits role: persistent, stamp-gated ============
        unsigned short* As = (unsigned short*)smem;             // 128x64
        unsigned short* Bs = As + 128 * 64;                     // 192x64
        int lb = blockIdx.x - NWG;
        int wid = tid >> 6;
        int wr = wid & 1, wc = wid >> 1;                        // 2x3 wave grid
        int fr = lane & 15, r7 = lane & 7, sb = lane >> 4;
        int rA = lane >> 3, slp = (lane & 7) ^ rA;              // B pre-swizzle
        for (int tile = lb; tile < NTILES; tile += LBLK) {
            int mt = tile / NBI, nbi = tile % NBI;
            int m0 = mt * 128, n0 = nbi * 192;
            f32x4 acc[4][4] = {};
            for (int kt = 0; kt < 8; ++kt) {
                __syncthreads();   // LDS reuse guard (prev kt reads / prev tile)
                int ko = kt * 64;
                // B: global_load_lds staging (Ebf written by prior kernel: safe)
#pragma unroll
                for (int i = 0; i < 4; ++i) {
                    int brow = n0 + wid * 8 + i * 48 + rA;
                    if (brow > Vq - 1) brow = Vq - 1;           // tail clamp
                    __builtin_amdgcn_global_load_lds(
                        (g_void*)(Ebf + (long)brow * Hq + ko + slp * 8),
                        (l_void*)(Bs + (wid * 8 + i * 48) * 64), 16, 0, 0);
                }
                // A: coherent stamped loads from Hpk (stamp = gate + data)
                for (int task = tid; task < 1024; task += 384) {
                    int r = task >> 3, g = task & 7;
                    int ts = mt * 8 + (r >> 4);
                    const u64* src = Hpk + (long)ts * 8192 + (r & 15) * 512 + ko + g * 8;
                    u64 v[8];
                    bool ok;
                    int guard = 0;
                    do {
                        ok = true;
#pragma unroll
                        for (int k = 0; k < 8; ++k)
                            v[k] = __hip_atomic_load(&src[k], __ATOMIC_RELAXED,
                                                     __HIP_MEMORY_SCOPE_AGENT);
#pragma unroll
                        for (int k = 0; k < 8; ++k)
                            ok = ok && ((int)(v[k] >> 32) == ts + 1);
                        if (!ok) __builtin_amdgcn_s_sleep(16);
                    } while (!ok && ++guard < (1 << 16));
                    short8 pk;
#pragma unroll
                    for (int k = 0; k < 8; ++k) pk[k] = (short)(v[k] >> 16);
                    *(short8*)&As[r * 64 + ((g ^ (r & 7)) << 3)] = pk;
                }
                __syncthreads();   // drains glds vmcnt + LDS writes
#pragma unroll
                for (int ks = 0; ks < 2; ++ks) {
                    short8 af[4], bfr[4];
#pragma unroll
                    for (int f = 0; f < 4; ++f) {
                        af[f]  = *(const short8*)&As[(wr * 64 + f * 16 + fr) * 64 +
                                                     (((sb + ks * 4) ^ r7) << 3)];
                        bfr[f] = *(const short8*)&Bs[(wc * 64 + f * 16 + fr) * 64 +
                                                     (((sb + ks * 4) ^ r7) << 3)];
                    }
#pragma unroll
                    for (int fm = 0; fm < 4; ++fm)
#pragma unroll
                        for (int fn = 0; fn < 4; ++fn)
                            acc[fm][fn] = __builtin_amdgcn_mfma_f32_16x16x32_bf16(
                                af[fm], bfr[fn], acc[fm][fn], 0, 0, 0);
                }
            }
#pragma unroll
            for (int fn = 0; fn < 4; ++fn) {
                int v = n0 + wc * 64 + fn * 16 + fr;
                if (v < Vq) {
                    float bo = b_out[v];
#pragma unroll
                    for (int fm = 0; fm < 4; ++fm) {
#pragma unroll
                        for (int q = 0; q < 4; ++q) {
                            int m = m0 + wr * 64 + fm * 16 + (lane >> 4) * 4 + q;
                            out[((long)(m & 15) * Tq + (m >> 4)) * Vq + v] =
                                acc[fm][fn][q] + bo;
                        }
                    }
                }
            }
        }
    }
}

// ---------------------------------------------------------------------------
extern "C" void kernel_launch(void* const* d_in, const int* in_sizes, int n_in,
                              void* d_out, int out_size, void* d_ws, size_t ws_size,
                              hipStream_t stream) {
    const float* h0    = (const float*)d_in[0];
    const int*   target= (const int*)d_in[1];
    const float* E     = (const float*)d_in[2];
    const float* Wih   = (const float*)d_in[3];
    const float* Whh   = (const float*)d_in[4];
    const float* b_ih  = (const float*)d_in[5];
    const float* b_hh  = (const float*)d_in[6];
    const float* b_out = (const float*)d_in[7];
    float* out = (float*)d_out;

    char* ws = (char*)d_ws;
    size_t off = 0;
    unsigned short* Ebf   = (unsigned short*)(ws + off); off += (size_t)Vq * Hq * 2;
    unsigned short* WihHi = (unsigned short*)(ws + off); off += (size_t)Gq * Hq * 2;
    unsigned short* WihLo = (unsigned short*)(ws + off); off += (size_t)Gq * Hq * 2;
    unsigned short* WhhHi = (unsigned short*)(ws + off); off += (size_t)Gq * Hq * 2;
    unsigned short* WhhLo = (unsigned short*)(ws + off); off += (size_t)Gq * Hq * 2;
    float*          gi_all= (float*)(ws + off);          off += (size_t)Tq * Bq * Gq * 4;
    u64*            Hpk   = (u64*)(ws + off);            off += (size_t)Tq * 8192 * 8;

    prep_kernel<<<dim3(2048), dim3(256), 0, stream>>>(E, Wih, Whh, Ebf, WihHi, WihLo,
                                                      WhhHi, WhhLo, Hpk);
    gi_kernel<<<dim3(Tq, 16), dim3(384), 0, stream>>>(target, E, WihHi, WihLo, b_ih, gi_all);
    fused_kernel<<<dim3(NWG + LBLK), dim3(384), 0, stream>>>(h0, WhhHi, WhhLo, b_hh,
                                                             gi_all, Hpk, Ebf, b_out, out);
}

// Round 7
// 1372.963 us; speedup vs baseline: 1.4234x; 1.4234x over previous
//
#include <hip/hip_runtime.h>
#include <hip/hip_bf16.h>
#include <math.h>

#define Bq 16
#define Tq 256
#define Hq 512
#define Vq 32000
#define Gq 1536
#define NWG 16
#define LBLK 384           // persistent logits blocks
#define NBI 167            // ceil(32000/192) N-tiles
#define NTILES (32 * NBI)  // 32 m-tiles (8 timesteps each) x 167

typedef __attribute__((ext_vector_type(8))) short short8;
typedef __attribute__((ext_vector_type(4))) float f32x4;
typedef __attribute__((ext_vector_type(2))) unsigned long long u64x2;
typedef unsigned long long u64;

typedef const __attribute__((address_space(1))) void g_void;
typedef __attribute__((address_space(3))) void l_void;

__device__ __forceinline__ unsigned short f2bf(float f) {
    union { float f; unsigned int u; } v; v.f = f;
    unsigned int r = v.u + 0x7fffu + ((v.u >> 16) & 1u);
    return (unsigned short)(r >> 16);
}
__device__ __forceinline__ float bf2f(unsigned short h) {
    union { unsigned int u; float f; } v; v.u = ((unsigned int)h) << 16;
    return v.f;
}
__device__ __forceinline__ float sigm(float x) { return 1.0f / (1.0f + __expf(-x)); }
__device__ __forceinline__ float tanh_fast(float x) {
    float e = __expf(-2.0f * x);
    return (1.0f - e) / (1.0f + e);
}

// ---------------------------------------------------------------------------
// prep: cast E->bf16; split W_ih/W_hh; zero the 16 producer flags
// ---------------------------------------------------------------------------
__global__ void prep_kernel(const float* __restrict__ E, const float* __restrict__ Wih,
                            const float* __restrict__ Whh,
                            unsigned short* __restrict__ Ebf,
                            unsigned short* __restrict__ WihHi, unsigned short* __restrict__ WihLo,
                            unsigned short* __restrict__ WhhHi, unsigned short* __restrict__ WhhLo,
                            int* __restrict__ flags) {
    long tid = (long)blockIdx.x * blockDim.x + threadIdx.x;
    long stride = (long)gridDim.x * blockDim.x;
    for (long i = tid; i < (long)Vq * Hq; i += stride) Ebf[i] = f2bf(E[i]);
    for (long i = tid; i < (long)Gq * Hq; i += stride) {
        float w = Wih[i]; unsigned short hi = f2bf(w);
        WihHi[i] = hi; WihLo[i] = f2bf(w - bf2f(hi));
        w = Whh[i]; hi = f2bf(w);
        WhhHi[i] = hi; WhhLo[i] = f2bf(w - bf2f(hi));
    }
    if (tid < 512) flags[tid] = 0;
}

// ---------------------------------------------------------------------------
// gi: gi_all[t,b,:] = E[tok(t,b)] @ W_ih^T + b_ih   (split-bf16)
// ---------------------------------------------------------------------------
__launch_bounds__(384)
__global__ void gi_kernel(const int* __restrict__ target, const float* __restrict__ E,
                          const unsigned short* __restrict__ WihHi,
                          const unsigned short* __restrict__ WihLo,
                          const float* __restrict__ b_ih, float* __restrict__ gi_all) {
    __shared__ __align__(16) unsigned short Ahi[16][520];
    __shared__ __align__(16) unsigned short Alo[16][520];
    __shared__ int toks[16];
    int t = blockIdx.x, gb = blockIdx.y;
    int tid = threadIdx.x;
    if (tid < 16) toks[tid] = (t == 0) ? 1 : target[tid * Tq + (t - 1)];  // START=1
    __syncthreads();
    for (int idx = tid; idx < 16 * Hq; idx += 384) {
        int r = idx >> 9, k = idx & 511;
        float v = E[(long)toks[r] * Hq + k];
        unsigned short hi = f2bf(v);
        Ahi[r][k] = hi; Alo[r][k] = f2bf(v - bf2f(hi));
    }
    __syncthreads();
    int wave = tid >> 6, lane = tid & 63;
    int gcb = gb * 96 + wave * 16;
    int row = lane & 15, kg = (lane >> 4) * 8;
    const unsigned short* bh = WihHi + (long)(gcb + row) * Hq;
    const unsigned short* bl = WihLo + (long)(gcb + row) * Hq;
    f32x4 aHH = {0,0,0,0}, aHL = {0,0,0,0}, aLH = {0,0,0,0};
#pragma unroll
    for (int ks = 0; ks < 16; ++ks) {
        int k0 = ks * 32 + kg;
        short8 ah = *(const short8*)&Ahi[row][k0];
        short8 al = *(const short8*)&Alo[row][k0];
        short8 wh = *(const short8*)&bh[k0];
        short8 wl = *(const short8*)&bl[k0];
        aHH = __builtin_amdgcn_mfma_f32_16x16x32_bf16(ah, wh, aHH, 0, 0, 0);
        aHL = __builtin_amdgcn_mfma_f32_16x16x32_bf16(ah, wl, aHL, 0, 0, 0);
        aLH = __builtin_amdgcn_mfma_f32_16x16x32_bf16(al, wh, aLH, 0, 0, 0);
    }
    int g = gcb + row;
    float bi = b_ih[g];
#pragma unroll
    for (int q = 0; q < 4; ++q) {
        int b = (lane >> 4) * 4 + q;
        gi_all[((long)(t * 16 + b)) * Gq + g] = aHH[q] + aHL[q] + aLH[q] + bi;
    }
}

// ---------------------------------------------------------------------------
// fused: blocks 0..15 = rnn (R4-validated core); blocks 16..399 = persistent
// logits consumers. Control = 16 coherent flags (tiny polls); data = Hpk
// write-once words, coherent-stored by producers (drained BEFORE flag store),
// read by consumers with PLAIN CACHED loads after the flag gate.
// Capacity: 400 blocks x 42KB LDS/384thr/128VGPR -> 2 blocks/CU, 512 slots.
// ---------------------------------------------------------------------------
__launch_bounds__(384, 1)
__global__ void fused_kernel(const float* __restrict__ h0,
                             const unsigned short* __restrict__ WhhHi,
                             const unsigned short* __restrict__ WhhLo,
                             const float* __restrict__ b_hh,
                             const float* __restrict__ gi_all,
                             u64* Hpk,
                             const unsigned short* __restrict__ Ebf,
                             const float* __restrict__ b_out,
                             float* __restrict__ out,
                             int* flags) {
    __shared__ __align__(16) char smem[41984];
    int tid = threadIdx.x;
    int lane = tid & 63;

    if (blockIdx.x < NWG) {
        // ================= RNN role (R4 core, 973us-validated) =============
        __builtin_amdgcn_s_setprio(1);
        unsigned short (*Ahi)[520] = (unsigned short (*)[520])smem;
        unsigned short (*Alo)[520] = (unsigned short (*)[520])(smem + 16640);
        float (*gbuf)[16][33] = (float (*)[16][33])(smem + 33280);
        int w = blockIdx.x;
        int wave = tid >> 6;
        int gate = wave >> 1;
        int gcol = gate * 512 + w * 32 + (wave & 1) * 16;
        int row = lane & 15, kg = (lane >> 4) * 8;
        const unsigned short* bhp = WhhHi + (long)(gcol + row) * Hq;
        const unsigned short* blp = WhhLo + (long)(gcol + row) * Hq;
        short8 Bh[16], Bl[16];
#pragma unroll
        for (int ks = 0; ks < 16; ++ks) {
            Bh[ks] = *(const short8*)&bhp[ks * 32 + kg];
            Bl[ks] = *(const short8*)&blp[ks * 32 + kg];
        }
        float bhh = b_hh[gcol + row];
        float gin[4];
#pragma unroll
        for (int q = 0; q < 4; ++q) {
            int b = (lane >> 4) * 4 + q;
            gin[q] = gi_all[(long)b * Gq + (gcol + row)];
        }
        int flo = (lane & 15) * 32;
        for (int t = 0; t < Tq; ++t) {
            if (t == 0) {
                for (int idx = tid; idx < Bq * Hq; idx += 384) {
                    float v = h0[idx];
                    unsigned short hi = f2bf(v);
                    Ahi[idx >> 9][idx & 511] = hi;
                    Alo[idx >> 9][idx & 511] = f2bf(v - bf2f(hi));
                }
            } else {
                int guard = 0;
                while (guard < (1 << 15)) {
                    int fv = __hip_atomic_load(&flags[flo], __ATOMIC_RELAXED,
                                               __HIP_MEMORY_SCOPE_AGENT);
                    if (__all(fv >= t)) break;
                    __builtin_amdgcn_s_sleep(1);
                    ++guard;
                }
                asm volatile("" ::: "memory");
                const u64* src = Hpk + (long)(t - 1) * 4096;
                u64 vb[11];
#pragma unroll
                for (int i = 0; i < 10; ++i)
                    vb[i] = __hip_atomic_load(&src[tid + i * 384], __ATOMIC_RELAXED,
                                              __HIP_MEMORY_SCOPE_AGENT);
                if (tid < 256)
                    vb[10] = __hip_atomic_load(&src[tid + 3840], __ATOMIC_RELAXED,
                                               __HIP_MEMORY_SCOPE_AGENT);
#pragma unroll
                for (int i = 0; i < 10; ++i) {
                    int p = tid + i * 384;
                    unsigned int e0 = (unsigned int)vb[i], e1 = (unsigned int)(vb[i] >> 32);
                    int b = p >> 8, j = (p & 255) * 2;
                    *(unsigned int*)&Ahi[b][j] = (e0 >> 16) | (e1 & 0xFFFF0000u);
                    *(unsigned int*)&Alo[b][j] = (e0 & 0xFFFFu) | (e1 << 16);
                }
                if (tid < 256) {
                    int p = tid + 3840;
                    unsigned int e0 = (unsigned int)vb[10], e1 = (unsigned int)(vb[10] >> 32);
                    int b = p >> 8, j = (p & 255) * 2;
                    *(unsigned int*)&Ahi[b][j] = (e0 >> 16) | (e1 & 0xFFFF0000u);
                    *(unsigned int*)&Alo[b][j] = (e0 & 0xFFFFu) | (e1 << 16);
                }
            }
            __syncthreads();
            f32x4 xHH = {0,0,0,0}, xHL = {0,0,0,0}, xLH = {0,0,0,0};
            f32x4 yHH = {0,0,0,0}, yHL = {0,0,0,0}, yLH = {0,0,0,0};
#pragma unroll
            for (int ks = 0; ks < 8; ++ks) {
                int k0 = ks * 32 + kg;
                short8 ah = *(const short8*)&Ahi[row][k0];
                short8 al = *(const short8*)&Alo[row][k0];
                xHH = __builtin_amdgcn_mfma_f32_16x16x32_bf16(ah, Bh[ks], xHH, 0, 0, 0);
                xHL = __builtin_amdgcn_mfma_f32_16x16x32_bf16(ah, Bl[ks], xHL, 0, 0, 0);
                xLH = __builtin_amdgcn_mfma_f32_16x16x32_bf16(al, Bh[ks], xLH, 0, 0, 0);
            }
#pragma unroll
            for (int ks = 8; ks < 16; ++ks) {
                int k0 = ks * 32 + kg;
                short8 ah = *(const short8*)&Ahi[row][k0];
                short8 al = *(const short8*)&Alo[row][k0];
                yHH = __builtin_amdgcn_mfma_f32_16x16x32_bf16(ah, Bh[ks], yHH, 0, 0, 0);
                yHL = __builtin_amdgcn_mfma_f32_16x16x32_bf16(ah, Bl[ks], yHL, 0, 0, 0);
                yLH = __builtin_amdgcn_mfma_f32_16x16x32_bf16(al, Bh[ks], yLH, 0, 0, 0);
            }
            int jj = (wave & 1) * 16 + row;
#pragma unroll
            for (int q = 0; q < 4; ++q) {
                int b = (lane >> 4) * 4 + q;
                float ghv = (xHH[q] + yHH[q]) + (xHL[q] + yHL[q]) + (xLH[q] + yLH[q]) + bhh;
                if (gate < 2) gbuf[gate][b][jj] = ghv + gin[q];
                else { gbuf[2][b][jj] = gin[q]; gbuf[3][b][jj] = ghv; }
            }
            __syncthreads();
            if (tid < 256) {
                int b = tid >> 4, jp = tid & 15;
                int j0 = jp * 2, j1 = j0 + 1;
                int jc0 = w * 32 + j0;
                float r0 = sigm(gbuf[0][b][j0]);
                float z0 = sigm(gbuf[1][b][j0]);
                float n0 = tanh_fast(gbuf[2][b][j0] + r0 * gbuf[3][b][j0]);
                float hp0 = bf2f(Ahi[b][jc0]) + bf2f(Alo[b][jc0]);
                float hn0 = (1.0f - z0) * n0 + z0 * hp0;
                float r1 = sigm(gbuf[0][b][j1]);
                float z1 = sigm(gbuf[1][b][j1]);
                float n1 = tanh_fast(gbuf[2][b][j1] + r1 * gbuf[3][b][j1]);
                float hp1 = bf2f(Ahi[b][jc0 + 1]) + bf2f(Alo[b][jc0 + 1]);
                float hn1 = (1.0f - z1) * n1 + z1 * hp1;
                unsigned short h0h = f2bf(hn0), h1h = f2bf(hn1);
                unsigned short h0l = f2bf(hn0 - bf2f(h0h)), h1l = f2bf(hn1 - bf2f(h1h));
                unsigned int e0 = ((unsigned int)h0h << 16) | h0l;
                unsigned int e1 = ((unsigned int)h1h << 16) | h1l;
                __hip_atomic_store(&Hpk[(long)t * 4096 + b * 256 + w * 16 + jp],
                                   ((u64)e1 << 32) | e0,
                                   __ATOMIC_RELAXED, __HIP_MEMORY_SCOPE_AGENT);
            }
            __syncthreads();  // drains vmcnt(0): all h stores at coherent point
            int tp = (t + 1 < Tq) ? (t + 1) : t;
#pragma unroll
            for (int q = 0; q < 4; ++q) {
                int b = (lane >> 4) * 4 + q;
                gin[q] = gi_all[((long)(tp * 16 + b)) * Gq + (gcol + row)];
            }
            if (tid == 0)
                __hip_atomic_store(&flags[w * 32], t + 1, __ATOMIC_RELAXED,
                                   __HIP_MEMORY_SCOPE_AGENT);
        }
    } else {
        // ============ logits role: flag-gated, cached data reads ===========
        unsigned short* As = (unsigned short*)smem;              // 128x64
        unsigned short* Bs = As + 128 * 64;                      // 192x64
        int lb = blockIdx.x - NWG;
        int wid = tid >> 6;
        int wr = wid & 1, wc = wid >> 1;                         // 2x3 wave grid
        int fr = lane & 15, r7 = lane & 7, sb = lane >> 4;
        int rA = lane >> 3, slp = (lane & 7) ^ rA;               // B pre-swizzle
        for (int tile = lb; tile < NTILES; tile += LBLK) {
            int mt = tile / NBI, nbi = tile % NBI;
            int m0 = mt * 128, n0 = nbi * 192;
            // ---- gate: all 16 producer flags >= (mt+1)*8 (tiny coherent poll)
            if (tid < 64) {
                int need = (mt + 1) * 8;
                int guard = 0;
                while (guard < (1 << 18)) {
                    int fv = __hip_atomic_load(&flags[(lane & 15) * 32],
                                               __ATOMIC_RELAXED, __HIP_MEMORY_SCOPE_AGENT);
                    if (__all(fv >= need)) break;
                    __builtin_amdgcn_s_sleep(127);
                    ++guard;
                }
            }
            __syncthreads();   // gate + LDS reuse guard vs prev tile
            f32x4 acc[4][4] = {};
            const u64* srcA = Hpk + (long)(mt * 8) * 4096;
            for (int kt = 0; kt < 8; ++kt) {
                if (kt) __syncthreads();
                int ko = kt * 64;
                // B: global_load_lds staging (Ebf is kernel-boundary stable)
#pragma unroll
                for (int i = 0; i < 4; ++i) {
                    int brow = n0 + wid * 8 + i * 48 + rA;
                    if (brow > Vq - 1) brow = Vq - 1;
                    __builtin_amdgcn_global_load_lds(
                        (g_void*)(Ebf + (long)brow * Hq + ko + slp * 8),
                        (l_void*)(Bs + (wid * 8 + i * 48) * 64), 16, 0, 0);
                }
                // A: PLAIN cached 16B loads of write-once Hpk words
                for (int p = tid; p < 2048; p += 384) {
                    int r = p >> 4, c = p & 15;       // row 0..127, 16B chunk
                    u64x2 v = *(const u64x2*)&srcA[(long)(r >> 4) * 4096 +
                                                   (r & 15) * 256 + kt * 32 + c * 2];
                    unsigned long long packed =
                        ((v[0] >> 16) & 0xFFFFull) | (((v[0] >> 48) & 0xFFFFull) << 16) |
                        (((v[1] >> 16) & 0xFFFFull) << 32) | ((v[1] >> 48) << 48);
                    int s = c >> 1, half = (c & 1) * 4;
                    *(unsigned long long*)&As[r * 64 + ((s ^ (r & 7)) << 3) + half] = packed;
                }
                __syncthreads();   // drains glds vmcnt + LDS writes
#pragma unroll
                for (int ks = 0; ks < 2; ++ks) {
                    short8 af[4], bfr[4];
#pragma unroll
                    for (int f = 0; f < 4; ++f) {
                        af[f]  = *(const short8*)&As[(wr * 64 + f * 16 + fr) * 64 +
                                                     (((sb + ks * 4) ^ r7) << 3)];
                        bfr[f] = *(const short8*)&Bs[(wc * 64 + f * 16 + fr) * 64 +
                                                     (((sb + ks * 4) ^ r7) << 3)];
                    }
#pragma unroll
                    for (int fm = 0; fm < 4; ++fm)
#pragma unroll
                        for (int fn = 0; fn < 4; ++fn)
                            acc[fm][fn] = __builtin_amdgcn_mfma_f32_16x16x32_bf16(
                                af[fm], bfr[fn], acc[fm][fn], 0, 0, 0);
                }
            }
#pragma unroll
            for (int fn = 0; fn < 4; ++fn) {
                int v = n0 + wc * 64 + fn * 16 + fr;
                if (v < Vq) {
                    float bo = b_out[v];
#pragma unroll
                    for (int fm = 0; fm < 4; ++fm) {
#pragma unroll
                        for (int q = 0; q < 4; ++q) {
                            int m = m0 + wr * 64 + fm * 16 + (lane >> 4) * 4 + q;
                            out[((long)(m & 15) * Tq + (m >> 4)) * Vq + v] =
                                acc[fm][fn][q] + bo;
                        }
                    }
                }
            }
        }
    }
}

// ---------------------------------------------------------------------------
extern "C" void kernel_launch(void* const* d_in, const int* in_sizes, int n_in,
                              void* d_out, int out_size, void* d_ws, size_t ws_size,
                              hipStream_t stream) {
    const float* h0    = (const float*)d_in[0];
    const int*   target= (const int*)d_in[1];
    const float* E     = (const float*)d_in[2];
    const float* Wih   = (const float*)d_in[3];
    const float* Whh   = (const float*)d_in[4];
    const float* b_ih  = (const float*)d_in[5];
    const float* b_hh  = (const float*)d_in[6];
    const float* b_out = (const float*)d_in[7];
    float* out = (float*)d_out;

    char* ws = (char*)d_ws;
    size_t off = 0;
    unsigned short* Ebf   = (unsigned short*)(ws + off); off += (size_t)Vq * Hq * 2;
    unsigned short* WihHi = (unsigned short*)(ws + off); off += (size_t)Gq * Hq * 2;
    unsigned short* WihLo = (unsigned short*)(ws + off); off += (size_t)Gq * Hq * 2;
    unsigned short* WhhHi = (unsigned short*)(ws + off); off += (size_t)Gq * Hq * 2;
    unsigned short* WhhLo = (unsigned short*)(ws + off); off += (size_t)Gq * Hq * 2;
    float*          gi_all= (float*)(ws + off);          off += (size_t)Tq * Bq * Gq * 4;
    u64*            Hpk   = (u64*)(ws + off);            off += (size_t)Tq * 4096 * 8;
    int*            flags = (int*)(ws + off);            off += 512 * 4;

    prep_kernel<<<dim3(2048), dim3(256), 0, stream>>>(E, Wih, Whh, Ebf, WihHi, WihLo,
                                                      WhhHi, WhhLo, flags);
    gi_kernel<<<dim3(Tq, 16), dim3(384), 0, stream>>>(target, E, WihHi, WihLo, b_ih, gi_all);
    fused_kernel<<<dim3(NWG + LBLK), dim3(384), 0, stream>>>(h0, WhhHi, WhhLo, b_hh,
                                                             gi_all, Hpk, Ebf, b_out, out,
                                                             flags);
}

// Round 8
// 951.740 us; speedup vs baseline: 2.0533x; 1.4426x over previous
//
#include <hip/hip_runtime.h>
#include <hip/hip_bf16.h>
#include <math.h>

#define Bq 16
#define Tq 256
#define Hq 512
#define Vq 32000
#define Gq 1536
#define NWG 16
#define LBLK 240           // persistent logits blocks (16+240 = 256 = 1/CU)
#define NBI 167            // ceil(32000/192) N-tiles
#define NTILES (32 * NBI)  // 32 m-tiles (8 timesteps each) x 167

typedef __attribute__((ext_vector_type(8))) short short8;
typedef __attribute__((ext_vector_type(4))) float f32x4;
typedef __attribute__((ext_vector_type(2))) unsigned long long u64x2;
typedef unsigned long long u64;

typedef const __attribute__((address_space(1))) void g_void;
typedef __attribute__((address_space(3))) void l_void;

__device__ __forceinline__ unsigned short f2bf(float f) {
    union { float f; unsigned int u; } v; v.f = f;
    unsigned int r = v.u + 0x7fffu + ((v.u >> 16) & 1u);
    return (unsigned short)(r >> 16);
}
__device__ __forceinline__ float bf2f(unsigned short h) {
    union { unsigned int u; float f; } v; v.u = ((unsigned int)h) << 16;
    return v.f;
}
__device__ __forceinline__ float sigm(float x) { return 1.0f / (1.0f + __expf(-x)); }
__device__ __forceinline__ float tanh_fast(float x) {
    float e = __expf(-2.0f * x);
    return (1.0f - e) / (1.0f + e);
}

// ---------------------------------------------------------------------------
// prep: cast E->bf16; split W_ih/W_hh; zero the 16 producer flags
// ---------------------------------------------------------------------------
__global__ void prep_kernel(const float* __restrict__ E, const float* __restrict__ Wih,
                            const float* __restrict__ Whh,
                            unsigned short* __restrict__ Ebf,
                            unsigned short* __restrict__ WihHi, unsigned short* __restrict__ WihLo,
                            unsigned short* __restrict__ WhhHi, unsigned short* __restrict__ WhhLo,
                            int* __restrict__ flags) {
    long tid = (long)blockIdx.x * blockDim.x + threadIdx.x;
    long stride = (long)gridDim.x * blockDim.x;
    for (long i = tid; i < (long)Vq * Hq; i += stride) Ebf[i] = f2bf(E[i]);
    for (long i = tid; i < (long)Gq * Hq; i += stride) {
        float w = Wih[i]; unsigned short hi = f2bf(w);
        WihHi[i] = hi; WihLo[i] = f2bf(w - bf2f(hi));
        w = Whh[i]; hi = f2bf(w);
        WhhHi[i] = hi; WhhLo[i] = f2bf(w - bf2f(hi));
    }
    if (tid < 512) flags[tid] = 0;
}

// ---------------------------------------------------------------------------
// gi: gi_all[t,b,:] = E[tok(t,b)] @ W_ih^T + b_ih   (split-bf16)
// ---------------------------------------------------------------------------
__launch_bounds__(384)
__global__ void gi_kernel(const int* __restrict__ target, const float* __restrict__ E,
                          const unsigned short* __restrict__ WihHi,
                          const unsigned short* __restrict__ WihLo,
                          const float* __restrict__ b_ih, float* __restrict__ gi_all) {
    __shared__ __align__(16) unsigned short Ahi[16][520];
    __shared__ __align__(16) unsigned short Alo[16][520];
    __shared__ int toks[16];
    int t = blockIdx.x, gb = blockIdx.y;
    int tid = threadIdx.x;
    if (tid < 16) toks[tid] = (t == 0) ? 1 : target[tid * Tq + (t - 1)];  // START=1
    __syncthreads();
    for (int idx = tid; idx < 16 * Hq; idx += 384) {
        int r = idx >> 9, k = idx & 511;
        float v = E[(long)toks[r] * Hq + k];
        unsigned short hi = f2bf(v);
        Ahi[r][k] = hi; Alo[r][k] = f2bf(v - bf2f(hi));
    }
    __syncthreads();
    int wave = tid >> 6, lane = tid & 63;
    int gcb = gb * 96 + wave * 16;
    int row = lane & 15, kg = (lane >> 4) * 8;
    const unsigned short* bh = WihHi + (long)(gcb + row) * Hq;
    const unsigned short* bl = WihLo + (long)(gcb + row) * Hq;
    f32x4 aHH = {0,0,0,0}, aHL = {0,0,0,0}, aLH = {0,0,0,0};
#pragma unroll
    for (int ks = 0; ks < 16; ++ks) {
        int k0 = ks * 32 + kg;
        short8 ah = *(const short8*)&Ahi[row][k0];
        short8 al = *(const short8*)&Alo[row][k0];
        short8 wh = *(const short8*)&bh[k0];
        short8 wl = *(const short8*)&bl[k0];
        aHH = __builtin_amdgcn_mfma_f32_16x16x32_bf16(ah, wh, aHH, 0, 0, 0);
        aHL = __builtin_amdgcn_mfma_f32_16x16x32_bf16(ah, wl, aHL, 0, 0, 0);
        aLH = __builtin_amdgcn_mfma_f32_16x16x32_bf16(al, wh, aLH, 0, 0, 0);
    }
    int g = gcb + row;
    float bi = b_ih[g];
#pragma unroll
    for (int q = 0; q < 4; ++q) {
        int b = (lane >> 4) * 4 + q;
        gi_all[((long)(t * 16 + b)) * Gq + g] = aHH[q] + aHL[q] + aLH[q] + bi;
    }
}

// ---------------------------------------------------------------------------
// fused: blocks 0..15 = rnn (exclusive CUs at grid=256); 16..255 = logits.
// Control = 16 coherent flags; data = write-once Hpk words (producer:
// relaxed agent stores drained BEFORE flag; consumer: PLAIN CACHED loads —
// region touched once/launch, kernel-boundary acquire kills stale lines).
// ---------------------------------------------------------------------------
__launch_bounds__(384, 1)
__global__ void fused_kernel(const float* __restrict__ h0,
                             const unsigned short* __restrict__ WhhHi,
                             const unsigned short* __restrict__ WhhLo,
                             const float* __restrict__ b_hh,
                             const float* __restrict__ gi_all,
                             u64* Hpk,
                             const unsigned short* __restrict__ Ebf,
                             const float* __restrict__ b_out,
                             float* __restrict__ out,
                             int* flags) {
    __shared__ __align__(16) char smem[41984];
    int tid = threadIdx.x;
    int lane = tid & 63;

    if (blockIdx.x < NWG) {
        // ================= RNN role =============
        __builtin_amdgcn_s_setprio(1);
        unsigned short (*Ahi)[520] = (unsigned short (*)[520])smem;
        unsigned short (*Alo)[520] = (unsigned short (*)[520])(smem + 16640);
        float (*gbuf)[16][33] = (float (*)[16][33])(smem + 33280);
        int w = blockIdx.x;
        int wave = tid >> 6;
        int gate = wave >> 1;
        int gcol = gate * 512 + w * 32 + (wave & 1) * 16;
        int row = lane & 15, kg = (lane >> 4) * 8;
        const unsigned short* bhp = WhhHi + (long)(gcol + row) * Hq;
        const unsigned short* blp = WhhLo + (long)(gcol + row) * Hq;
        short8 Bh[16], Bl[16];
#pragma unroll
        for (int ks = 0; ks < 16; ++ks) {
            Bh[ks] = *(const short8*)&bhp[ks * 32 + kg];
            Bl[ks] = *(const short8*)&blp[ks * 32 + kg];
        }
        float bhh = b_hh[gcol + row];
        float gin[4];
#pragma unroll
        for (int q = 0; q < 4; ++q) {
            int b = (lane >> 4) * 4 + q;
            gin[q] = gi_all[(long)b * Gq + (gcol + row)];
        }
        int flo = (lane & 15) * 32;
        for (int t = 0; t < Tq; ++t) {
            if (t == 0) {
                for (int idx = tid; idx < Bq * Hq; idx += 384) {
                    float v = h0[idx];
                    unsigned short hi = f2bf(v);
                    Ahi[idx >> 9][idx & 511] = hi;
                    Alo[idx >> 9][idx & 511] = f2bf(v - bf2f(hi));
                }
            } else {
                int guard = 0;
                while (guard < (1 << 15)) {
                    int fv = __hip_atomic_load(&flags[flo], __ATOMIC_RELAXED,
                                               __HIP_MEMORY_SCOPE_AGENT);
                    if (__all(fv >= t)) break;
                    __builtin_amdgcn_s_sleep(1);
                    ++guard;
                }
                asm volatile("" ::: "memory");
                // plain cached 16B loads of write-once words (one RTT batch)
                const u64x2* src = (const u64x2*)(Hpk + (long)(t - 1) * 4096);
                u64x2 vb[6];
#pragma unroll
                for (int i = 0; i < 5; ++i) vb[i] = src[tid + i * 384];
                if (tid < 128) vb[5] = src[1920 + tid];
#pragma unroll
                for (int i = 0; i < 5; ++i) {
                    int c = tid + i * 384;           // chunk: words 2c, 2c+1
                    int p = c * 2;
                    int b = p >> 8, j = (p & 255) * 2;   // 4 cols j..j+3
                    unsigned int e0a = (unsigned int)vb[i][0], e1a = (unsigned int)(vb[i][0] >> 32);
                    unsigned int e0b = (unsigned int)vb[i][1], e1b = (unsigned int)(vb[i][1] >> 32);
                    unsigned int hiA = (e0a >> 16) | (e1a & 0xFFFF0000u);
                    unsigned int hiB = (e0b >> 16) | (e1b & 0xFFFF0000u);
                    unsigned int loA = (e0a & 0xFFFFu) | (e1a << 16);
                    unsigned int loB = (e0b & 0xFFFFu) | (e1b << 16);
                    *(u64*)&Ahi[b][j] = (u64)hiA | ((u64)hiB << 32);
                    *(u64*)&Alo[b][j] = (u64)loA | ((u64)loB << 32);
                }
                if (tid < 128) {
                    int c = 1920 + tid;
                    int p = c * 2;
                    int b = p >> 8, j = (p & 255) * 2;
                    unsigned int e0a = (unsigned int)vb[5][0], e1a = (unsigned int)(vb[5][0] >> 32);
                    unsigned int e0b = (unsigned int)vb[5][1], e1b = (unsigned int)(vb[5][1] >> 32);
                    unsigned int hiA = (e0a >> 16) | (e1a & 0xFFFF0000u);
                    unsigned int hiB = (e0b >> 16) | (e1b & 0xFFFF0000u);
                    unsigned int loA = (e0a & 0xFFFFu) | (e1a << 16);
                    unsigned int loB = (e0b & 0xFFFFu) | (e1b << 16);
                    *(u64*)&Ahi[b][j] = (u64)hiA | ((u64)hiB << 32);
                    *(u64*)&Alo[b][j] = (u64)loA | ((u64)loB << 32);
                }
            }
            __syncthreads();
            f32x4 xHH = {0,0,0,0}, xHL = {0,0,0,0}, xLH = {0,0,0,0};
            f32x4 yHH = {0,0,0,0}, yHL = {0,0,0,0}, yLH = {0,0,0,0};
#pragma unroll
            for (int ks = 0; ks < 8; ++ks) {
                int k0 = ks * 32 + kg;
                short8 ah = *(const short8*)&Ahi[row][k0];
                short8 al = *(const short8*)&Alo[row][k0];
                xHH = __builtin_amdgcn_mfma_f32_16x16x32_bf16(ah, Bh[ks], xHH, 0, 0, 0);
                xHL = __builtin_amdgcn_mfma_f32_16x16x32_bf16(ah, Bl[ks], xHL, 0, 0, 0);
                xLH = __builtin_amdgcn_mfma_f32_16x16x32_bf16(al, Bh[ks], xLH, 0, 0, 0);
            }
#pragma unroll
            for (int ks = 8; ks < 16; ++ks) {
                int k0 = ks * 32 + kg;
                short8 ah = *(const short8*)&Ahi[row][k0];
                short8 al = *(const short8*)&Alo[row][k0];
                yHH = __builtin_amdgcn_mfma_f32_16x16x32_bf16(ah, Bh[ks], yHH, 0, 0, 0);
                yHL = __builtin_amdgcn_mfma_f32_16x16x32_bf16(ah, Bl[ks], yHL, 0, 0, 0);
                yLH = __builtin_amdgcn_mfma_f32_16x16x32_bf16(al, Bh[ks], yLH, 0, 0, 0);
            }
            int jj = (wave & 1) * 16 + row;
#pragma unroll
            for (int q = 0; q < 4; ++q) {
                int b = (lane >> 4) * 4 + q;
                float ghv = (xHH[q] + yHH[q]) + (xHL[q] + yHL[q]) + (xLH[q] + yLH[q]) + bhh;
                if (gate < 2) gbuf[gate][b][jj] = ghv + gin[q];
                else { gbuf[2][b][jj] = gin[q]; gbuf[3][b][jj] = ghv; }
            }
            __syncthreads();
            if (tid < 256) {
                int b = tid >> 4, jp = tid & 15;
                int j0 = jp * 2, j1 = j0 + 1;
                int jc0 = w * 32 + j0;
                float r0 = sigm(gbuf[0][b][j0]);
                float z0 = sigm(gbuf[1][b][j0]);
                float n0 = tanh_fast(gbuf[2][b][j0] + r0 * gbuf[3][b][j0]);
                float hp0 = bf2f(Ahi[b][jc0]) + bf2f(Alo[b][jc0]);
                float hn0 = (1.0f - z0) * n0 + z0 * hp0;
                float r1 = sigm(gbuf[0][b][j1]);
                float z1 = sigm(gbuf[1][b][j1]);
                float n1 = tanh_fast(gbuf[2][b][j1] + r1 * gbuf[3][b][j1]);
                float hp1 = bf2f(Ahi[b][jc0 + 1]) + bf2f(Alo[b][jc0 + 1]);
                float hn1 = (1.0f - z1) * n1 + z1 * hp1;
                unsigned short h0h = f2bf(hn0), h1h = f2bf(hn1);
                unsigned short h0l = f2bf(hn0 - bf2f(h0h)), h1l = f2bf(hn1 - bf2f(h1h));
                unsigned int e0 = ((unsigned int)h0h << 16) | h0l;
                unsigned int e1 = ((unsigned int)h1h << 16) | h1l;
                __hip_atomic_store(&Hpk[(long)t * 4096 + b * 256 + w * 16 + jp],
                                   ((u64)e1 << 32) | e0,
                                   __ATOMIC_RELAXED, __HIP_MEMORY_SCOPE_AGENT);
            }
            __syncthreads();  // drains vmcnt(0): all h stores at coherent point
            int tp = (t + 1 < Tq) ? (t + 1) : t;
#pragma unroll
            for (int q = 0; q < 4; ++q) {
                int b = (lane >> 4) * 4 + q;
                gin[q] = gi_all[((long)(tp * 16 + b)) * Gq + (gcol + row)];
            }
            if (tid == 0)
                __hip_atomic_store(&flags[w * 32], t + 1, __ATOMIC_RELAXED,
                                   __HIP_MEMORY_SCOPE_AGENT);
        }
    } else {
        // ============ logits role: flag-gated, cached data reads ===========
        unsigned short* As = (unsigned short*)smem;              // 128x64
        unsigned short* Bs = As + 128 * 64;                      // 192x64
        int lb = blockIdx.x - NWG;
        int wid = tid >> 6;
        int wr = wid & 1, wc = wid >> 1;                         // 2x3 wave grid
        int fr = lane & 15, r7 = lane & 7, sb = lane >> 4;
        int rA = lane >> 3, slp = (lane & 7) ^ rA;               // B pre-swizzle
        for (int tile = lb; tile < NTILES; tile += LBLK) {
            int mt = tile / NBI, nbi = tile % NBI;
            int m0 = mt * 128, n0 = nbi * 192;
            if (tid < 64) {
                int need = (mt + 1) * 8;
                int guard = 0;
                while (guard < (1 << 18)) {
                    int fv = __hip_atomic_load(&flags[(lane & 15) * 32],
                                               __ATOMIC_RELAXED, __HIP_MEMORY_SCOPE_AGENT);
                    if (__all(fv >= need)) break;
                    __builtin_amdgcn_s_sleep(127);
                    ++guard;
                }
            }
            __syncthreads();   // gate + LDS reuse guard vs prev tile
            f32x4 acc[4][4] = {};
            const u64* srcA = Hpk + (long)(mt * 8) * 4096;
            for (int kt = 0; kt < 8; ++kt) {
                if (kt) __syncthreads();
                int ko = kt * 64;
#pragma unroll
                for (int i = 0; i < 4; ++i) {
                    int brow = n0 + wid * 8 + i * 48 + rA;
                    if (brow > Vq - 1) brow = Vq - 1;
                    __builtin_amdgcn_global_load_lds(
                        (g_void*)(Ebf + (long)brow * Hq + ko + slp * 8),
                        (l_void*)(Bs + (wid * 8 + i * 48) * 64), 16, 0, 0);
                }
                for (int p = tid; p < 2048; p += 384) {
                    int r = p >> 4, c = p & 15;       // row 0..127, 16B chunk
                    u64x2 v = *(const u64x2*)&srcA[(long)(r >> 4) * 4096 +
                                                   (r & 15) * 256 + kt * 32 + c * 2];
                    unsigned long long packed =
                        ((v[0] >> 16) & 0xFFFFull) | (((v[0] >> 48) & 0xFFFFull) << 16) |
                        (((v[1] >> 16) & 0xFFFFull) << 32) | ((v[1] >> 48) << 48);
                    int s = c >> 1, half = (c & 1) * 4;
                    *(unsigned long long*)&As[r * 64 + ((s ^ (r & 7)) << 3) + half] = packed;
                }
                __syncthreads();
#pragma unroll
                for (int ks = 0; ks < 2; ++ks) {
                    short8 af[4], bfr[4];
#pragma unroll
                    for (int f = 0; f < 4; ++f) {
                        af[f]  = *(const short8*)&As[(wr * 64 + f * 16 + fr) * 64 +
                                                     (((sb + ks * 4) ^ r7) << 3)];
                        bfr[f] = *(const short8*)&Bs[(wc * 64 + f * 16 + fr) * 64 +
                                                     (((sb + ks * 4) ^ r7) << 3)];
                    }
#pragma unroll
                    for (int fm = 0; fm < 4; ++fm)
#pragma unroll
                        for (int fn = 0; fn < 4; ++fn)
                            acc[fm][fn] = __builtin_amdgcn_mfma_f32_16x16x32_bf16(
                                af[fm], bfr[fn], acc[fm][fn], 0, 0, 0);
                }
            }
#pragma unroll
            for (int fn = 0; fn < 4; ++fn) {
                int v = n0 + wc * 64 + fn * 16 + fr;
                if (v < Vq) {
                    float bo = b_out[v];
#pragma unroll
                    for (int fm = 0; fm < 4; ++fm) {
#pragma unroll
                        for (int q = 0; q < 4; ++q) {
                            int m = m0 + wr * 64 + fm * 16 + (lane >> 4) * 4 + q;
                            // nt store: don't allocate LLC -> E stays resident
                            __builtin_nontemporal_store(
                                acc[fm][fn][q] + bo,
                                &out[((long)(m & 15) * Tq + (m >> 4)) * Vq + v]);
                        }
                    }
                }
            }
        }
    }
}

// ---------------------------------------------------------------------------
extern "C" void kernel_launch(void* const* d_in, const int* in_sizes, int n_in,
                              void* d_out, int out_size, void* d_ws, size_t ws_size,
                              hipStream_t stream) {
    const float* h0    = (const float*)d_in[0];
    const int*   target= (const int*)d_in[1];
    const float* E     = (const float*)d_in[2];
    const float* Wih   = (const float*)d_in[3];
    const float* Whh   = (const float*)d_in[4];
    const float* b_ih  = (const float*)d_in[5];
    const float* b_hh  = (const float*)d_in[6];
    const float* b_out = (const float*)d_in[7];
    float* out = (float*)d_out;

    char* ws = (char*)d_ws;
    size_t off = 0;
    unsigned short* Ebf   = (unsigned short*)(ws + off); off += (size_t)Vq * Hq * 2;
    unsigned short* WihHi = (unsigned short*)(ws + off); off += (size_t)Gq * Hq * 2;
    unsigned short* WihLo = (unsigned short*)(ws + off); off += (size_t)Gq * Hq * 2;
    unsigned short* WhhHi = (unsigned short*)(ws + off); off += (size_t)Gq * Hq * 2;
    unsigned short* WhhLo = (unsigned short*)(ws + off); off += (size_t)Gq * Hq * 2;
    float*          gi_all= (float*)(ws + off);          off += (size_t)Tq * Bq * Gq * 4;
    u64*            Hpk   = (u64*)(ws + off);            off += (size_t)Tq * 4096 * 8;
    int*            flags = (int*)(ws + off);            off += 512 * 4;

    prep_kernel<<<dim3(2048), dim3(256), 0, stream>>>(E, Wih, Whh, Ebf, WihHi, WihLo,
                                                      WhhHi, WhhLo, flags);
    gi_kernel<<<dim3(Tq, 16), dim3(384), 0, stream>>>(target, E, WihHi, WihLo, b_ih, gi_all);
    fused_kernel<<<dim3(NWG + LBLK), dim3(384), 0, stream>>>(h0, WhhHi, WhhLo, b_hh,
                                                             gi_all, Hpk, Ebf, b_out, out,
                                                             flags);
}